// Round 9
// baseline (236.231 us; speedup 1.0000x reference)
//
#include <hip/hip_runtime.h>
#include <math.h>

#define B_    32
#define NV    32768
#define LA    64
#define DIM   128
#define OUTD  7
#define TOPK  10
#define CHUNK 1024
#define NCH   (NV / CHUNK)   // 32
#define NMW   (NV / 32)      // 1024 mask words per batch
#define MAXU  (LA * TOPK)    // 640
#define NSEG  16             // gather segments per batch

typedef unsigned long long u64;

// ---------------- K1: per-(b,l) sample threshold, 4 waves/task ------------------
// grid (LA, B_), block 256. Samples 2048 contiguous verts. Zeros cnt/maskG/done.
__global__ void k1_threshold(const float* __restrict__ pos,
                             const float* __restrict__ lig,
                             float* __restrict__ T, unsigned int* __restrict__ cnt,
                             unsigned int* __restrict__ maskG,
                             unsigned int* __restrict__ doneF,
                             unsigned int* __restrict__ doneG) {
  __shared__ float m[4 * TOPK];
  const int l = blockIdx.x, b = blockIdx.y;
  const int tid = threadIdx.x, w = tid >> 6, lane = tid & 63;
  const int bl = b * LA + l;
  if (tid == 0) cnt[bl] = 0u;
  if (tid < 16) maskG[b * NMW + l * 16 + tid] = 0u;
  if (l == 0 && tid == 0) doneF[b] = 0u;
  if (l == 0 && tid == 1) doneG[b] = 0u;
  const float lx = lig[bl * 3 + 0];
  const float ly = lig[bl * 3 + 1];
  const float lz = lig[bl * 3 + 2];
  float s[TOPK];
#pragma unroll
  for (int i = 0; i < TOPK; ++i) s[i] = INFINITY;
  const float* pb = pos + (size_t)b * NV * 3;
#pragma unroll
  for (int k = 0; k < 8; ++k) {
    int v = w * 512 + lane + 64 * k;
    float dx = pb[v * 3 + 0] - lx;
    float dy = pb[v * 3 + 1] - ly;
    float dz = pb[v * 3 + 2] - lz;
    float d2 = fmaf(dx, dx, fmaf(dy, dy, dz * dz));
    if (d2 < s[TOPK - 1]) {
      s[TOPK - 1] = d2;
#pragma unroll
      for (int i = TOPK - 1; i >= 1; --i)
        if (s[i] < s[i - 1]) { float t = s[i]; s[i] = s[i - 1]; s[i - 1] = t; }
    }
  }
  for (int r = 0; r < TOPK; ++r) {
    float v = s[0];
#pragma unroll
    for (int o = 1; o < 64; o <<= 1) v = fminf(v, __shfl_xor(v, o, 64));
    if (s[0] == v) {
#pragma unroll
      for (int i = 0; i < TOPK - 1; ++i) s[i] = s[i + 1];
      s[TOPK - 1] = INFINITY;
    }
    if (lane == r) m[w * TOPK + r] = v;
  }
  __syncthreads();
  if (w == 0) {
    float val = (lane < 4 * TOPK) ? m[lane] : INFINITY;
    float T10 = 0.f;
    for (int r = 0; r < TOPK; ++r) {
      float v = val;
#pragma unroll
      for (int o = 1; o < 64; o <<= 1) v = fminf(v, __shfl_xor(v, o, 64));
      T10 = v;
      if (val == v) val = INFINITY;  // dup-consume only enlarges T: safe
    }
    if (lane == 0) T[bl] = T10;
  }
}

// ---------------- K2: filter; last block per batch does exact select ------------
// grid (NCH, B_) = 1024 blocks, block 256.
__global__ void k2_filter_select(const float* __restrict__ pos,
                                 const float* __restrict__ lig,
                                 const float* __restrict__ T,
                                 unsigned int* __restrict__ cnt,
                                 int* __restrict__ cand, int cap,
                                 unsigned int* __restrict__ doneF,
                                 unsigned int* __restrict__ maskG) {
  __shared__ float4 vp[CHUNK];  // 16 KB
  __shared__ int lastFlag;
  const int c = blockIdx.x, b = blockIdx.y;
  const int tid = threadIdx.x, w = tid >> 6, lane = tid & 63;
  const int base = c * CHUNK;
  const float* pb = pos + ((size_t)b * NV + base) * 3;
  for (int j = tid; j < CHUNK * 3; j += 256) {
    int v = j / 3, comp = j - 3 * v;
    float val = pb[j];
    if (comp == 0) vp[v].x = val;
    else if (comp == 1) vp[v].y = val;
    else vp[v].z = val;
  }
  __syncthreads();
  for (int v = tid; v < CHUNK; v += 256) {
    float px = vp[v].x, py = vp[v].y, pz = vp[v].z;
    vp[v].w = fmaf(px, px, fmaf(py, py, pz * pz));
  }
  __syncthreads();
  {
    const int lg = tid >> 4, vl = tid & 15;
    float Ax[4], Ay[4], Az[4], TH[4];
#pragma unroll
    for (int j = 0; j < 4; ++j) {
      int l = lg + 16 * j;
      float lx = lig[(b * LA + l) * 3 + 0];
      float ly = lig[(b * LA + l) * 3 + 1];
      float lz = lig[(b * LA + l) * 3 + 2];
      Ax[j] = -2.f * lx; Ay[j] = -2.f * ly; Az[j] = -2.f * lz;
      TH[j] = T[b * LA + l] + 0.01f - (lx * lx + ly * ly + lz * lz);
    }
    for (int k = 0; k < CHUNK / 16; ++k) {
      int v = vl + 16 * k;
      float4 p = vp[v];
#pragma unroll
      for (int j = 0; j < 4; ++j) {
        float t = fmaf(p.x, Ax[j], fmaf(p.y, Ay[j], fmaf(p.z, Az[j], p.w)));
        if (t <= TH[j]) {
          int l = lg + 16 * j;
          unsigned pidx = atomicAdd(&cnt[b * LA + l], 1u);
          if (pidx < (unsigned)cap) cand[(size_t)(b * LA + l) * cap + pidx] = base + v;
        }
      }
    }
  }
  // --- last-block-per-batch: exact top-10 select for all 64 ligands -----------
  __syncthreads();               // all filter stores at least in L2
  if (tid == 0) {
    __threadfence();             // flush to device-coherent point
    unsigned old = atomicAdd(&doneF[b], 1u);
    lastFlag = (old == NCH - 1) ? 1 : 0;
  }
  __syncthreads();
  if (!lastFlag) return;
  __threadfence();               // acquire: invalidate stale cached lines
  const float* pbb = pos + (size_t)b * NV * 3;
  for (int j = 0; j < 16; ++j) {
    const int l = w * 16 + j;
    const int bl = b * LA + l;
    const float lx = lig[bl * 3 + 0], ly = lig[bl * 3 + 1], lz = lig[bl * 3 + 2];
    int n = (int)min(cnt[bl], (unsigned)cap);
    u64 s[TOPK];
#pragma unroll
    for (int i = 0; i < TOPK; ++i) s[i] = 0xFFFFFFFFFFFFFFFFull;
    for (int i = lane; i < n; i += 64) {
      int v = cand[(size_t)bl * cap + i];
      float dx = pbb[v * 3 + 0] - lx;
      float dy = pbb[v * 3 + 1] - ly;
      float dz = pbb[v * 3 + 2] - lz;
      float d2 = fmaf(dx, dx, fmaf(dy, dy, dz * dz));
      u64 key = ((u64)__float_as_uint(d2) << 32) | (unsigned)v;
      if (key < s[TOPK - 1]) {
        s[TOPK - 1] = key;
#pragma unroll
        for (int i2 = TOPK - 1; i2 >= 1; --i2)
          if (s[i2] < s[i2 - 1]) { u64 t = s[i2]; s[i2] = s[i2 - 1]; s[i2 - 1] = t; }
      }
    }
    int prev = 0, myidx = 0;
    for (int r = 0; r < TOPK; ++r) {
      u64 v = s[0];
#pragma unroll
      for (int o = 1; o < 64; o <<= 1) {
        u64 other = __shfl_xor(v, o, 64);
        v = (other < v) ? other : v;
      }
      if (s[0] == v) {
#pragma unroll
        for (int i = 0; i < TOPK - 1; ++i) s[i] = s[i + 1];
        s[TOPK - 1] = 0xFFFFFFFFFFFFFFFFull;
      }
      int idx = (int)(unsigned)(v & 0xFFFFFFFFu);
      if ((v >> 32) == 0xFFFFFFFFull) idx = prev;  // pad guard (n<10 impossible)
      prev = idx;
      if (lane == r) myidx = idx;
    }
    if (lane < TOPK)
      atomicOr(&maskG[b * NMW + (myidx >> 5)], 1u << (myidx & 31));
  }
}

// ---------------- K3: compaction + segment gather; last block per batch -> MLP --
// grid (NSEG, B_) = 512 blocks, block 256.
__global__ void k3_gather_mlp(const float* __restrict__ x,
                              const unsigned int* __restrict__ maskG,
                              double* __restrict__ partial,
                              unsigned int* __restrict__ doneG,
                              const float* __restrict__ W1, const float* __restrict__ b1,
                              const float* __restrict__ gam, const float* __restrict__ bet,
                              const float* __restrict__ rm, const float* __restrict__ rv,
                              const float* __restrict__ W2, const float* __restrict__ b2,
                              float* __restrict__ out) {
  __shared__ int list[MAXU];     // 2.56 KB
  __shared__ int wtot[4], wbase[4];
  __shared__ int cntS, lastFlag;
  __shared__ double red[2][DIM]; // 2 KB
  __shared__ float embS[DIM];
  __shared__ float hpart[2][DIM];
  __shared__ float hS[DIM];
  const int seg = blockIdx.x, b = blockIdx.y, tid = threadIdx.x;
  const int w = tid >> 6, lane = tid & 63;
  unsigned int wd[4];
  int c = 0;
#pragma unroll
  for (int k = 0; k < 4; ++k) {
    wd[k] = maskG[b * NMW + tid * 4 + k];
    c += __popc(wd[k]);
  }
  int incl = c;
#pragma unroll
  for (int o = 1; o < 64; o <<= 1) {
    int up = __shfl_up(incl, o, 64);
    if (lane >= o) incl += up;
  }
  if (lane == 63) wtot[w] = incl;
  __syncthreads();
  if (tid == 0) {
    int s = 0;
#pragma unroll
    for (int i = 0; i < 4; ++i) { wbase[i] = s; s += wtot[i]; }
    cntS = s;
  }
  __syncthreads();
  int p = wbase[w] + incl - c;
#pragma unroll
  for (int k = 0; k < 4; ++k) {
    unsigned int bits = wd[k];
    while (bits) {
      int bit = __ffs(bits) - 1;
      list[p++] = (tid * 4 + k) * 32 + bit;
      bits &= bits - 1;
    }
  }
  __syncthreads();
  const int n = cntS;
  const int r0 = (seg * n) / NSEG, r1 = ((seg + 1) * n) / NSEG;
  const int slot = tid >> 7, col = tid & 127;
  const float* xb = x + (size_t)b * NV * DIM;
  double a0 = 0, a1 = 0, a2 = 0, a3 = 0;
  int i = r0 + slot;
  for (; i + 6 < r1; i += 8) {
    float v0 = xb[(size_t)list[i + 0] * DIM + col];
    float v1 = xb[(size_t)list[i + 2] * DIM + col];
    float v2 = xb[(size_t)list[i + 4] * DIM + col];
    float v3 = xb[(size_t)list[i + 6] * DIM + col];
    a0 += (double)v0; a1 += (double)v1; a2 += (double)v2; a3 += (double)v3;
  }
  for (; i < r1; i += 2) a0 += (double)xb[(size_t)list[i] * DIM + col];
  red[slot][col] = ((a0 + a1) + (a2 + a3));
  __syncthreads();
  if (tid < DIM)
    partial[((size_t)b * NSEG + seg) * DIM + tid] = red[0][tid] + red[1][tid];
  // --- last-block-per-batch: reduce partials + top_net MLP --------------------
  __syncthreads();
  if (tid == 0) {
    __threadfence();
    unsigned old = atomicAdd(&doneG[b], 1u);
    lastFlag = (old == NSEG - 1) ? 1 : 0;
  }
  __syncthreads();
  if (!lastFlag) return;
  __threadfence();
  if (tid < DIM) {
    double s = 0;
#pragma unroll
    for (int sg = 0; sg < NSEG; ++sg)
      s += partial[((size_t)b * NSEG + sg) * DIM + tid];
    embS[tid] = (float)(s / (double)n);
  }
  __syncthreads();
  {
    const int d = tid & 127, half = tid >> 7;
    float hp = 0.f;
    const int dd0 = half * 64;
#pragma unroll 8
    for (int dd = dd0; dd < dd0 + 64; ++dd) hp = fmaf(embS[dd], W1[dd * DIM + d], hp);
    hpart[half][d] = hp;
  }
  __syncthreads();
  if (tid < DIM) {
    float h = hpart[0][tid] + hpart[1][tid] + b1[tid];
    h = (h - rm[tid]) / sqrtf(rv[tid] + 1e-5f) * gam[tid] + bet[tid];
    h = h / (1.f + expf(-h));
    hS[tid] = h;
  }
  __syncthreads();
  if (tid < OUTD * 16) {
    const int o = tid >> 4, g = tid & 15;
    float pacc = 0.f;
#pragma unroll
    for (int dd = g * 8; dd < g * 8 + 8; ++dd) pacc = fmaf(hS[dd], W2[dd * OUTD + o], pacc);
#pragma unroll
    for (int off = 8; off >= 1; off >>= 1) pacc += __shfl_down(pacc, off, 16);
    if (g == 0) out[b * OUTD + o] = pacc + b2[o];
  }
}

extern "C" void kernel_launch(void* const* d_in, const int* in_sizes, int n_in,
                              void* d_out, int out_size, void* d_ws, size_t ws_size,
                              hipStream_t stream) {
  const float* pos  = (const float*)d_in[0];
  const float* x    = (const float*)d_in[1];
  const float* lig  = (const float*)d_in[2];
  const float* W1   = (const float*)d_in[3];
  const float* b1   = (const float*)d_in[4];
  const float* gam  = (const float*)d_in[5];
  const float* bet  = (const float*)d_in[6];
  const float* rm   = (const float*)d_in[7];
  const float* rv   = (const float*)d_in[8];
  const float* W2   = (const float*)d_in[9];
  const float* b2   = (const float*)d_in[10];
  float* out = (float*)d_out;

  // workspace carve-up
  char* ws = (char*)d_ws;
  const int NBL = B_ * LA;  // 2048
  float* T            = (float*)(ws);                     // 8 KB
  unsigned int* cnt   = (unsigned int*)(ws + 8192);       // 8 KB
  unsigned int* maskG = (unsigned int*)(ws + 16384);      // 128 KB
  unsigned int* doneF = (unsigned int*)(ws + 147456);     // 128 B
  unsigned int* doneG = (unsigned int*)(ws + 147584);     // 128 B
  double* partial     = (double*)(ws + 147712);           // 512 KB
  int* cand           = (int*)(ws + 672000);
  size_t fixed = 672000;
  size_t avail = ws_size > fixed ? ws_size - fixed : 0;
  int cap = (int)(avail / ((size_t)NBL * 4));
  if (cap > 1024) cap = 1024;
  if (cap < 16) cap = 16;

  k1_threshold<<<dim3(LA, B_), 256, 0, stream>>>(pos, lig, T, cnt, maskG, doneF, doneG);
  k2_filter_select<<<dim3(NCH, B_), 256, 0, stream>>>(pos, lig, T, cnt, cand, cap,
                                                      doneF, maskG);
  k3_gather_mlp<<<dim3(NSEG, B_), 256, 0, stream>>>(x, maskG, partial, doneG,
                                                    W1, b1, gam, bet, rm, rv,
                                                    W2, b2, out);
}

// Round 10
// 200.626 us; speedup vs baseline: 1.1775x; 1.1775x over previous
//
#include <hip/hip_runtime.h>
#include <math.h>

#define B_    32
#define NV    32768
#define LA    64
#define DIM   128
#define OUTD  7
#define TOPK  10
#define KCH   12             // per-chunk kept ranks (10 + 2 guard)
#define CHUNK 1024
#define NCH   (NV / CHUNK)   // 32
#define NCAND (NCH * KCH)    // 384 candidates per (b,l)
#define NMW   (NV / 32)      // 1024 mask words per batch
#define MAXU  (LA * TOPK)    // 640

typedef unsigned long long u64;

// ---------------- KA: per-chunk exact top-12 per ligand, fixed slots ------------
// grid (NCH, B_) = 1024 blocks, 256 threads. Thread (lg=tid>>4, vl=tid&15):
// ligands {lg+16j, j=0..3}, verts {vl+16k, k=0..63}. No atomics, no counters.
__global__ void ka_chunktop(const float* __restrict__ pos,
                            const float* __restrict__ lig,
                            int* __restrict__ cand) {
  __shared__ float4 vp[CHUNK];   // 16 KB: x,y,z,pp
  const int c = blockIdx.x, b = blockIdx.y, tid = threadIdx.x;
  const int base = c * CHUNK;
  const float* pb = pos + ((size_t)b * NV + base) * 3;
  for (int j = tid; j < CHUNK * 3; j += 256) {
    int v = j / 3, comp = j - 3 * v;
    float val = pb[j];
    if (comp == 0) vp[v].x = val;
    else if (comp == 1) vp[v].y = val;
    else vp[v].z = val;
  }
  __syncthreads();
  for (int v = tid; v < CHUNK; v += 256) {
    float px = vp[v].x, py = vp[v].y, pz = vp[v].z;
    vp[v].w = fmaf(px, px, fmaf(py, py, pz * pz));
  }
  __syncthreads();
  const int lg = tid >> 4, vl = tid & 15;
  for (int j = 0; j < 4; ++j) {
    const int l = lg + 16 * j;
    const int bl = b * LA + l;
    const float lx = lig[bl * 3 + 0];
    const float ly = lig[bl * 3 + 1];
    const float lz = lig[bl * 3 + 2];
    const float Ax = -2.f * lx, Ay = -2.f * ly, Az = -2.f * lz;
    const float Cl = fmaf(lx, lx, fmaf(ly, ly, lz * lz));
    u64 s[KCH];
#pragma unroll
    for (int i = 0; i < KCH; ++i) s[i] = 0xFFFFFFFFFFFFFFFFull;
    for (int k = 0; k < CHUNK / 16; ++k) {
      int v = vl + 16 * k;
      float4 p = vp[v];
      float d2 = fmaf(p.x, Ax, fmaf(p.y, Ay, fmaf(p.z, Az, p.w))) + Cl;
      d2 = fmaxf(d2, 0.f);
      u64 key = ((u64)__float_as_uint(d2) << 32) | (unsigned)(base + v);
      if (key < s[KCH - 1]) {
        s[KCH - 1] = key;
#pragma unroll
        for (int i2 = KCH - 1; i2 >= 1; --i2)
          if (s[i2] < s[i2 - 1]) { u64 t = s[i2]; s[i2] = s[i2 - 1]; s[i2 - 1] = t; }
      }
    }
    // 16-lane merge (keys unique, every thread holds 12 real keys): 12 rounds.
    int* slot = cand + (size_t)bl * NCAND + c * KCH;
    for (int r = 0; r < KCH; ++r) {
      u64 v = s[0];
#pragma unroll
      for (int o = 1; o < 16; o <<= 1) {
        u64 other = __shfl_xor(v, o, 64);
        v = (other < v) ? other : v;
      }
      if (s[0] == v) {
#pragma unroll
        for (int i = 0; i < KCH - 1; ++i) s[i] = s[i + 1];
        s[KCH - 1] = 0xFFFFFFFFFFFFFFFFull;
      }
      if (vl == r) slot[r] = (int)(unsigned)(v & 0xFFFFFFFFu);
    }
  }
}

// ---------------- KB: exact select + dedup + gather mean + MLP, one block/batch -
// grid B_, block 1024 (16 waves). Wave w: ligands 4w..4w+3 (select phase).
__global__ void kb_all(const float* __restrict__ pos, const float* __restrict__ x,
                       const float* __restrict__ lig, const int* __restrict__ cand,
                       const float* __restrict__ W1, const float* __restrict__ b1,
                       const float* __restrict__ gam, const float* __restrict__ bet,
                       const float* __restrict__ rm, const float* __restrict__ rv,
                       const float* __restrict__ W2, const float* __restrict__ b2,
                       float* __restrict__ out) {
  __shared__ unsigned maskL[NMW];        // 4 KB
  __shared__ int list[MAXU];             // 2.5 KB
  __shared__ double red[8][DIM];         // 8 KB
  __shared__ float embS[DIM];
  __shared__ float hpart[8][DIM];        // 4 KB
  __shared__ float hS[DIM];
  __shared__ int wtot[16], wbase[16], cntS;
  const int b = blockIdx.x, tid = threadIdx.x;
  const int w = tid >> 6, lane = tid & 63;
  for (int i = tid; i < NMW; i += 1024) maskL[i] = 0u;
  __syncthreads();
  // --- exact top-10 per lig over 384 fixed candidates (diff-of-squares) ---
  const float* pb = pos + (size_t)b * NV * 3;
  for (int j = 0; j < 4; ++j) {
    const int l = w * 4 + j;
    const int bl = b * LA + l;
    const float lx = lig[bl * 3 + 0];
    const float ly = lig[bl * 3 + 1];
    const float lz = lig[bl * 3 + 2];
    const int* cd = cand + (size_t)bl * NCAND;
    u64 s[TOPK];
#pragma unroll
    for (int i = 0; i < TOPK; ++i) s[i] = 0xFFFFFFFFFFFFFFFFull;
#pragma unroll
    for (int k = 0; k < NCAND / 64; ++k) {   // 6
      int v = cd[lane + 64 * k];
      float dx = pb[v * 3 + 0] - lx;
      float dy = pb[v * 3 + 1] - ly;
      float dz = pb[v * 3 + 2] - lz;
      float d2 = fmaf(dx, dx, fmaf(dy, dy, dz * dz));
      u64 key = ((u64)__float_as_uint(d2) << 32) | (unsigned)v;
      if (key < s[TOPK - 1]) {
        s[TOPK - 1] = key;
#pragma unroll
        for (int i2 = TOPK - 1; i2 >= 1; --i2)
          if (s[i2] < s[i2 - 1]) { u64 t = s[i2]; s[i2] = s[i2 - 1]; s[i2 - 1] = t; }
      }
    }
    // 64-lane merge (each vertex appears exactly once in cand: keys unique)
    int prev = 0, myidx = 0;
    for (int r = 0; r < TOPK; ++r) {
      u64 v = s[0];
#pragma unroll
      for (int o = 1; o < 64; o <<= 1) {
        u64 other = __shfl_xor(v, o, 64);
        v = (other < v) ? other : v;
      }
      if (s[0] == v) {
#pragma unroll
        for (int i = 0; i < TOPK - 1; ++i) s[i] = s[i + 1];
        s[TOPK - 1] = 0xFFFFFFFFFFFFFFFFull;
      }
      int idx = (int)(unsigned)(v & 0xFFFFFFFFu);
      if ((v >> 32) == 0xFFFFFFFFull) idx = prev;  // sentinel guard (unreachable)
      prev = idx;
      if (lane == r) myidx = idx;
    }
    if (lane < TOPK)
      atomicOr(&maskL[myidx >> 5], 1u << (myidx & 31));
  }
  __syncthreads();
  // --- dedup: block-wide exclusive scan over popcounts (deterministic) ---
  unsigned bits = maskL[tid];
  int c = __popc(bits);
  int incl = c;
#pragma unroll
  for (int o = 1; o < 64; o <<= 1) {
    int up = __shfl_up(incl, o, 64);
    if (lane >= o) incl += up;
  }
  if (lane == 63) wtot[w] = incl;
  __syncthreads();
  if (tid == 0) {
    int ssum = 0;
#pragma unroll
    for (int i = 0; i < 16; ++i) { wbase[i] = ssum; ssum += wtot[i]; }
    cntS = ssum;
  }
  __syncthreads();
  int p = wbase[w] + incl - c;
  while (bits) {
    int bit = __ffs(bits) - 1;
    list[p++] = tid * 32 + bit;
    bits &= bits - 1;
  }
  __syncthreads();
  const int n = cntS;
  // --- gather-sum (f64, fixed order): 8 row-slots x 128 cols ---
  const int slot = tid >> 7, col = tid & 127;
  const float* xb = x + (size_t)b * NV * DIM;
  double a0 = 0, a1 = 0, a2 = 0, a3 = 0;
  int i = slot;
  for (; i + 24 < n; i += 32) {
    float v0 = xb[(size_t)list[i +  0] * DIM + col];
    float v1 = xb[(size_t)list[i +  8] * DIM + col];
    float v2 = xb[(size_t)list[i + 16] * DIM + col];
    float v3 = xb[(size_t)list[i + 24] * DIM + col];
    a0 += (double)v0; a1 += (double)v1; a2 += (double)v2; a3 += (double)v3;
  }
  for (; i < n; i += 8) a0 += (double)xb[(size_t)list[i] * DIM + col];
  red[slot][col] = ((a0 + a1) + (a2 + a3));
  __syncthreads();
  if (tid < DIM) {
    double ssum = 0;
#pragma unroll
    for (int r = 0; r < 8; ++r) ssum += red[r][tid];
    embS[tid] = (float)(ssum / (double)n);
  }
  __syncthreads();
  // --- Linear1 (8-way split) + BN(eval) + SiLU ---
  {
    const int d = tid & 127, oct = tid >> 7;
    float hp = 0.f;
    const int dd0 = oct * 16;
#pragma unroll
    for (int dd = dd0; dd < dd0 + 16; ++dd) hp = fmaf(embS[dd], W1[dd * DIM + d], hp);
    hpart[oct][d] = hp;
  }
  __syncthreads();
  if (tid < DIM) {
    float h = b1[tid];
#pragma unroll
    for (int r = 0; r < 8; ++r) h += hpart[r][tid];
    h = (h - rm[tid]) / sqrtf(rv[tid] + 1e-5f) * gam[tid] + bet[tid];
    h = h / (1.f + expf(-h));
    hS[tid] = h;
  }
  __syncthreads();
  if (tid < OUTD * 16) {
    const int o = tid >> 4, g = tid & 15;
    float pacc = 0.f;
#pragma unroll
    for (int dd = g * 8; dd < g * 8 + 8; ++dd)
      pacc = fmaf(hS[dd], W2[dd * OUTD + o], pacc);
#pragma unroll
    for (int off = 8; off >= 1; off >>= 1) pacc += __shfl_down(pacc, off, 16);
    if (g == 0) out[b * OUTD + o] = pacc + b2[o];
  }
}

extern "C" void kernel_launch(void* const* d_in, const int* in_sizes, int n_in,
                              void* d_out, int out_size, void* d_ws, size_t ws_size,
                              hipStream_t stream) {
  const float* pos  = (const float*)d_in[0];
  const float* x    = (const float*)d_in[1];
  const float* lig  = (const float*)d_in[2];
  const float* W1   = (const float*)d_in[3];
  const float* b1   = (const float*)d_in[4];
  const float* gam  = (const float*)d_in[5];
  const float* bet  = (const float*)d_in[6];
  const float* rm   = (const float*)d_in[7];
  const float* rv   = (const float*)d_in[8];
  const float* W2   = (const float*)d_in[9];
  const float* b2   = (const float*)d_in[10];
  float* out = (float*)d_out;

  // workspace: cand [B*LA][NCAND] ints = 3.1 MB
  int* cand = (int*)d_ws;

  ka_chunktop<<<dim3(NCH, B_), 256, 0, stream>>>(pos, lig, cand);
  kb_all<<<B_, 1024, 0, stream>>>(pos, x, lig, cand, W1, b1, gam, bet, rm, rv,
                                  W2, b2, out);
}